// Round 9
// baseline (148.644 us; speedup 1.0000x reference)
//
#include <hip/hip_runtime.h>
#include <hip/hip_bf16.h>

// Problem constants
#define Bc 2
#define Nc 6
#define Cc 64
#define Hc 28
#define Wc 50
#define Dc 59
#define BHc 200
#define BWc 200
// BEV_X0 = BEV_Y0 = -50.0, RES = 0.5

#define NZ 640
#define ACC_ELEMS ((size_t)Bc * BHc * BWc * Cc)   // 5,120,000 floats
#define DT 2              // d's per block
#define NTILE 30          // ceil(59/2)
#define NBLK (12 * NTILE) // 360

// ---------------------------------------------------------------------------
__global__ __launch_bounds__(256) void fp_zero(float* __restrict__ acc)
{
    const size_t NF4 = ACC_ELEMS / 4;
    float4* a4 = (float4*)acc;
    size_t base = (size_t)blockIdx.x * 2048;
#pragma unroll
    for (int it = 0; it < 8; ++it) {
        size_t i = base + (size_t)it * 256 + threadIdx.x;
        if (i < NF4) a4[i] = make_float4(0.f, 0.f, 0.f, 0.f);
    }
}

// ---------------------------------------------------------------------------
// Fused lift-splat: block = (bn, d-pair). Reads feats/depth COALESCED from
// original layouts (w-contiguous), transposes F in LDS (XOR-swizzled), does
// the h-sum as a dense masked matmul (lane = c, depth via readlane), then
// one 64-lane atomic per (w,d). Geometry bit-exact vs reference; fast path
// guarded by 7 bitwise-zero structure checks, else exact slow path.
__global__ __launch_bounds__(256) void fp_fused(
    const float* __restrict__ feats,   // (B,N,C,H,W)
    const float* __restrict__ depth,   // (B,N,D,H,W)
    const float* __restrict__ Kmat,    // (B,N,3,3)
    const float* __restrict__ Emat,    // (B,N,4,4)
    float* __restrict__ acc)           // (B, BH*BW, C)
{
    // f_lds[h'][c][slot] : slot = (w>>2) ^ (c&15), f4 granules, w padded to 64
    __shared__ __align__(16) float f_lds[2][64][64];     // 32 KB
    __shared__ float dep_lds[DT][Hc][52];                 // 11.6 KB

    // XCD grouping: xcd-pair g hosts bn-trio {3g..3g+2}
    int bid  = blockIdx.x;
    int xcd  = bid & 7;
    int j    = bid >> 3;                 // 0..44
    int k    = (xcd & 1) * 45 + j;       // 0..89
    int g    = xcd >> 1;                 // 0..3
    int bn   = 3 * g + k / 30;
    int t    = k % 30;
    int b    = bn / Nc;
    int d0   = t * DT;

    int tid  = threadIdx.x;
    int lane = tid & 63;
    int q    = tid >> 6;                 // wave id 0..3

    const size_t HW = (size_t)Hc * Wc;
    const float* Fb = feats + (size_t)bn * Cc * HW;
    const float* Db = depth + (size_t)bn * Dc * HW;

    // ---- stage depth (both d's), coalesced float2 ----
    for (int i = tid; i < (DT * Hc * Wc) / 2; i += 256) {
        int dp  = i / 700;               // 700 = 28*25
        int rem = i % 700;
        int hh  = rem / 25;
        int w2  = rem % 25;
        int dg  = d0 + dp;
        float2 v = make_float2(0.f, 0.f);
        if (dg < Dc)
            v = *(const float2*)(Db + ((size_t)dg * Hc + hh) * Wc + 2 * w2);
        dep_lds[dp][hh][2 * w2]     = v.x;
        dep_lds[dp][hh][2 * w2 + 1] = v.y;
    }

    // ---- K inverse (exact f32 adjugate) ----
    const float* K = Kmat + (size_t)bn * 9;
    float k00 = K[0], k01 = K[1], k02 = K[2];
    float k10 = K[3], k11 = K[4], k12 = K[5];
    float k20 = K[6], k21 = K[7], k22 = K[8];
    float c00 = __fsub_rn(__fmul_rn(k11,k22), __fmul_rn(k12,k21));
    float c01 = __fsub_rn(__fmul_rn(k12,k20), __fmul_rn(k10,k22));
    float c02 = __fsub_rn(__fmul_rn(k10,k21), __fmul_rn(k11,k20));
    float det = __fadd_rn(__fadd_rn(__fmul_rn(k00,c00), __fmul_rn(k01,c01)), __fmul_rn(k02,c02));
    float i00 = __fdiv_rn(c00, det);
    float i01 = __fdiv_rn(__fsub_rn(__fmul_rn(k02,k21), __fmul_rn(k01,k22)), det);
    float i02 = __fdiv_rn(__fsub_rn(__fmul_rn(k01,k12), __fmul_rn(k02,k11)), det);
    float i10 = __fdiv_rn(c01, det);
    float i11 = __fdiv_rn(__fsub_rn(__fmul_rn(k00,k22), __fmul_rn(k02,k20)), det);
    float i12 = __fdiv_rn(__fsub_rn(__fmul_rn(k02,k10), __fmul_rn(k00,k12)), det);
    float i20 = __fdiv_rn(c02, det);
    float i21 = __fdiv_rn(__fsub_rn(__fmul_rn(k01,k20), __fmul_rn(k00,k21)), det);
    float i22 = __fdiv_rn(__fsub_rn(__fmul_rn(k00,k11), __fmul_rn(k01,k10)), det);

    const float* E = Emat + (size_t)bn * 16;
    float r00 = E[0], r01 = E[1], r02 = E[2],  tx = E[3];
    float r10 = E[4], r11 = E[5], r12 = E[6],  ty = E[7];
    float r20 = E[8], r21 = E[9], r22 = E[10], tz = E[11];

    // structural zero checks (bitwise +0.0f) -> fast path validity
    bool fast = (__float_as_uint(i01) == 0u) & (__float_as_uint(i10) == 0u) &
                (__float_as_uint(i21) == 0u) & (__float_as_uint(r01) == 0u) &
                (__float_as_uint(r11) == 0u) & (__float_as_uint(r20) == 0u) &
                (__float_as_uint(r22) == 0u);

    __syncthreads();                     // dep_lds ready

    float* accb = acc + (size_t)b * (BHc * BWc) * Cc;

    // ---- wave's 16 w-slots: f4-blocks {q, q+4, q+8, (q==0?12:13)} ----
    int wblk[4];
    wblk[0] = q; wblk[1] = q + 4; wblk[2] = q + 8; wblk[3] = (q == 0) ? 12 : 13;

    // ---- masked depth into lane=h registers (fast path) ----
    float mval[DT][16];
    {
        int hl = (lane < Hc) ? lane : 0;
#pragma unroll
        for (int dp = 0; dp < DT; ++dp) {
            // ez(d, h=lane) with exact-proxy chain (cx,cz -> 0, valid per checks)
            int dg = d0 + dp;
            float db = (float)(dg + 1);
            float py = __fmul_rn((float)lane, db);
            float cy = __fadd_rn(__fadd_rn(__fmul_rn(i10, 0.0f), __fmul_rn(i11, py)), __fmul_rn(i12, db));
            float ez = __fadd_rn(__fadd_rn(__fadd_rn(__fmul_rn(r20, 0.0f), __fmul_rn(r21, cy)), __fmul_rn(r22, 0.0f)), tz);
            bool zok = (ez > 0.0f) && (dg < Dc);
#pragma unroll
            for (int s = 0; s < 16; ++s) {
                int w = wblk[s >> 2] * 4 + (s & 3);
                float dv = dep_lds[dp][hl][w];   // w may be pad: garbage, discarded
                mval[dp][s] = zok ? dv : 0.0f;
            }
        }
    }

    // ---- bins per (w-slot, d'): pair-lane parallel exact chains ----
    int binv = -1;
    {
        int p = lane;                    // pair index
        if (p < 32) {
            int s  = p >> 1;
            int dp = p & 1;
            int w  = wblk[s >> 2] * 4 + (s & 3);
            int dg = d0 + dp;
            if (w < Wc && dg < Dc) {
                float db = (float)(dg + 1);
                float px = __fmul_rn((float)w, db);
                float pz = db;
                float cx = __fadd_rn(__fadd_rn(__fmul_rn(i00, px), __fmul_rn(i01, 0.0f)), __fmul_rn(i02, pz));
                float cz = __fadd_rn(__fadd_rn(__fmul_rn(i20, px), __fmul_rn(i21, 0.0f)), __fmul_rn(i22, pz));
                float ex = __fadd_rn(__fadd_rn(__fadd_rn(__fmul_rn(r00, cx), __fmul_rn(r01, 0.0f)), __fmul_rn(r02, cz)), tx);
                float ey = __fadd_rn(__fadd_rn(__fadd_rn(__fmul_rn(r10, cx), __fmul_rn(r11, 0.0f)), __fmul_rn(r12, cz)), ty);
                int bx = (int)(__fmul_rn(__fadd_rn(ex, 50.0f), 2.0f));
                int by = (int)(__fmul_rn(__fadd_rn(ey, 50.0f), 2.0f));
                if (bx >= 0 && bx < BWc && by >= 0 && by < BHc)
                    binv = by * BWc + bx;
            }
        }
    }

    float accv[DT][16];
#pragma unroll
    for (int dp = 0; dp < DT; ++dp)
#pragma unroll
        for (int s = 0; s < 16; ++s) accv[dp][s] = 0.0f;

    // ---- h-chunk loop: stage F slab (2 h), then dense masked matmul ----
    for (int hc = 0; hc < 14; ++hc) {
        __syncthreads();                 // previous chunk's reads done
        // stage: F[c][hc*2+h'][w] -> f_lds[h'][c][swizzled]
        for (int i = tid; i < 3200; i += 256) {
            int c   = i / 50;
            int rem = i % 50;
            int hp  = rem >= 25;
            int w2  = rem - hp * 25;
            int w   = 2 * w2;
            float2 v = *(const float2*)(Fb + ((size_t)c * Hc + hc * 2 + hp) * Wc + w);
            int slot0 = ((w >> 2) ^ (c & 15));
            f_lds[hp][c][slot0 * 4 + (w & 3)] = v.x;
            int w1 = w + 1;
            int slot1 = ((w1 >> 2) ^ (c & 15));
            f_lds[hp][c][slot1 * 4 + (w1 & 3)] = v.y;
        }
        __syncthreads();

        if (fast) {
#pragma unroll
            for (int hp = 0; hp < 2; ++hp) {
                int h = hc * 2 + hp;     // uniform (SGPR) readlane index
#pragma unroll
                for (int s4 = 0; s4 < 4; ++s4) {
                    const float4 f4 = *(const float4*)&f_lds[hp][lane][(wblk[s4] ^ (lane & 15)) * 4];
#pragma unroll
                    for (int dp = 0; dp < DT; ++dp) {
                        float d0v = __int_as_float(__builtin_amdgcn_readlane(__float_as_int(mval[dp][s4*4+0]), h));
                        float d1v = __int_as_float(__builtin_amdgcn_readlane(__float_as_int(mval[dp][s4*4+1]), h));
                        float d2v = __int_as_float(__builtin_amdgcn_readlane(__float_as_int(mval[dp][s4*4+2]), h));
                        float d3v = __int_as_float(__builtin_amdgcn_readlane(__float_as_int(mval[dp][s4*4+3]), h));
                        accv[dp][s4*4+0] = __builtin_fmaf(f4.x, d0v, accv[dp][s4*4+0]);
                        accv[dp][s4*4+1] = __builtin_fmaf(f4.y, d1v, accv[dp][s4*4+1]);
                        accv[dp][s4*4+2] = __builtin_fmaf(f4.z, d2v, accv[dp][s4*4+2]);
                        accv[dp][s4*4+3] = __builtin_fmaf(f4.w, d3v, accv[dp][s4*4+3]);
                    }
                }
            }
        } else {
            // exact slow path: per-(w,h,d) full chains + per-h atomics
            for (int hp = 0; hp < 2; ++hp) {
                int h = hc * 2 + hp;
                float yf = (float)h;
                for (int s = 0; s < 16; ++s) {
                    int w = wblk[s >> 2] * 4 + (s & 3);
                    if (w >= Wc) continue;
                    float xf = (float)w;
                    const float4 f4 = *(const float4*)&f_lds[hp][lane][(wblk[s >> 2] ^ (lane & 15)) * 4];
                    float fv = (s & 3) == 0 ? f4.x : (s & 3) == 1 ? f4.y : (s & 3) == 2 ? f4.z : f4.w;
                    for (int dp = 0; dp < DT; ++dp) {
                        int dg = d0 + dp;
                        if (dg >= Dc) continue;
                        float db = (float)(dg + 1);
                        float px = __fmul_rn(xf, db);
                        float py = __fmul_rn(yf, db);
                        float pz = db;
                        float cx = __fadd_rn(__fadd_rn(__fmul_rn(i00,px), __fmul_rn(i01,py)), __fmul_rn(i02,pz));
                        float cy = __fadd_rn(__fadd_rn(__fmul_rn(i10,px), __fmul_rn(i11,py)), __fmul_rn(i12,pz));
                        float cz = __fadd_rn(__fadd_rn(__fmul_rn(i20,px), __fmul_rn(i21,py)), __fmul_rn(i22,pz));
                        float ex = __fadd_rn(__fadd_rn(__fadd_rn(__fmul_rn(r00,cx), __fmul_rn(r01,cy)), __fmul_rn(r02,cz)), tx);
                        float ey = __fadd_rn(__fadd_rn(__fadd_rn(__fmul_rn(r10,cx), __fmul_rn(r11,cy)), __fmul_rn(r12,cz)), ty);
                        float ez = __fadd_rn(__fadd_rn(__fadd_rn(__fmul_rn(r20,cx), __fmul_rn(r21,cy)), __fmul_rn(r22,cz)), tz);
                        int bx = (int)(__fmul_rn(__fadd_rn(ex, 50.0f), 2.0f));
                        int by = (int)(__fmul_rn(__fadd_rn(ey, 50.0f), 2.0f));
                        if (bx >= 0 && bx < BWc && by >= 0 && by < BHc && ez > 0.0f) {
                            float dv = dep_lds[dp][h][w];
                            atomicAdd(&accb[(size_t)(by * BWc + bx) * Cc + lane],
                                      __fmul_rn(fv, dv));
                        }
                    }
                }
            }
        }
    }

    // ---- epilogue: one 64-lane atomic per (w,d) (fast path) ----
    if (fast) {
#pragma unroll
        for (int s = 0; s < 16; ++s) {
#pragma unroll
            for (int dp = 0; dp < DT; ++dp) {
                int p = s * 2 + dp;
                int sbin = __builtin_amdgcn_readlane(binv, p);
                if (sbin >= 0)
                    atomicAdd(&accb[(size_t)sbin * Cc + lane], accv[dp][s]);
            }
        }
    }
}

// (B, BH*BW, C) -> (B, C, BH*BW), LDS-tiled 64x64
__global__ __launch_bounds__(256) void fp_transpose_kernel(
    const float* __restrict__ acc, float* __restrict__ out)
{
    __shared__ float tile[64][65];
    const int P = BHc * BWc;
    int b = blockIdx.y;
    int p0 = blockIdx.x * 64;
    int tx = threadIdx.x & 63;
    int ty = threadIdx.x >> 6;

    const float* src = acc + (size_t)b * P * Cc;
#pragma unroll
    for (int i = 0; i < 16; ++i) {
        int row = ty * 16 + i;
        tile[row][tx] = src[(size_t)(p0 + row) * Cc + tx];
    }
    __syncthreads();
    float* dst = out + (size_t)b * Cc * P;
#pragma unroll
    for (int i = 0; i < 16; ++i) {
        int c = ty * 16 + i;
        dst[(size_t)c * P + p0 + tx] = tile[tx][c];
    }
}

extern "C" void kernel_launch(void* const* d_in, const int* in_sizes, int n_in,
                              void* d_out, int out_size, void* d_ws, size_t ws_size,
                              hipStream_t stream) {
    const float* feats = (const float*)d_in[0];
    const float* depth = (const float*)d_in[1];
    const float* Kmat  = (const float*)d_in[2];
    const float* Emat  = (const float*)d_in[3];
    float* out = (float*)d_out;
    float* acc = (float*)d_ws;

    fp_zero<<<NZ, 256, 0, stream>>>(acc);
    fp_fused<<<NBLK, 256, 0, stream>>>(feats, depth, Kmat, Emat, acc);
    fp_transpose_kernel<<<dim3((BHc * BWc) / 64, Bc), 256, 0, stream>>>(acc, out);
}

// Round 11
// 102.296 us; speedup vs baseline: 1.4531x; 1.4531x over previous
//
#include <hip/hip_runtime.h>
#include <hip/hip_bf16.h>

// Problem constants
#define Bc 2
#define Nc 6
#define Cc 64
#define Hc 28
#define Wc 50
#define Dc 59
#define BHc 200
#define BWc 200
// BEV_X0 = BEV_Y0 = -50.0, RES = 0.5

#define NZ 640
#define ACC_ELEMS ((size_t)Bc * BHc * BWc * Cc)   // 5,120,000 floats

#define W4N 13            // ceil(50/4) w-groups
#define DH 30             // d's per d-half
#define KPW 15            // d's per wave
#define NBLK (12 * W4N * 2)   // 312 blocks

// ---------------------------------------------------------------------------
__global__ __launch_bounds__(256) void fp_zero(float* __restrict__ acc)
{
    const size_t NF4 = ACC_ELEMS / 4;
    float4* a4 = (float4*)acc;
    size_t base = (size_t)blockIdx.x * 2048;
#pragma unroll
    for (int it = 0; it < 8; ++it) {
        size_t i = base + (size_t)it * 256 + threadIdx.x;
        if (i < NF4) a4[i] = make_float4(0.f, 0.f, 0.f, 0.f);
    }
}

// ---------------------------------------------------------------------------
// Scatter v7: block = (bn, w4, dhalf). 512 threads, ONE barrier.
// Staging: float2 w-contiguous loads from ORIGINAL layouts into LDS
//   f_lds[h][w'][c] (c-padded 65) and d_lds[d'][w'][h] (h-dim 29).
// Compute: wave = (w', dsub); per (w,d): exact scatter5 logic (lane-h
//   reference chains, ballot prim bin, readlane h-matmul, one wave atomic).
__global__ __launch_bounds__(512) void fp_scatter7(
    const float* __restrict__ feats,   // (B,N,C,H,W)
    const float* __restrict__ depth,   // (B,N,D,H,W)
    const float* __restrict__ Kmat,    // (B,N,3,3)
    const float* __restrict__ Emat,    // (B,N,4,4)
    float* __restrict__ acc)           // (B, BH*BW, C)
{
    __shared__ float f_lds[Hc][4][65];   // 29.1 KB  [h][w'][c]
    __shared__ float d_lds[DH][4][29];   // 13.9 KB  [d'][w'][h]

    // XCD-aware: xcd hosts 39 consecutive linear blocks
    int bid = blockIdx.x;
    int lin = (bid & 7) * 39 + (bid >> 3);    // bijective on [0,312)
    int bn    = lin / 26;
    int rest  = lin % 26;
    int w4    = rest >> 1;
    int dhalf = rest & 1;
    int b   = bn / Nc;
    int w0  = w4 * 4;
    int d0h = dhalf * DH;

    int tid  = threadIdx.x;
    int lane = tid & 63;
    int wid  = tid >> 6;                 // 0..7

    const size_t HW = (size_t)Hc * Wc;
    const float* Fb = feats + (size_t)bn * Cc * HW;
    const float* Db = depth + (size_t)bn * Dc * HW;

    // ---- stage feats: 64c x 28h x 4w as float2 (w-contiguous) ----
    for (int i = tid; i < Cc * Hc * 2; i += 512) {     // 3584
        int c  = i / 56;
        int j2 = i % 56;
        int hh = j2 >> 1;
        int p  = j2 & 1;
        int w  = w0 + 2 * p;
        if (w + 1 < Wc) {
            float2 v = *(const float2*)(Fb + ((size_t)c * Hc + hh) * Wc + w);
            f_lds[hh][2 * p][c]     = v.x;
            f_lds[hh][2 * p + 1][c] = v.y;
        } else if (w < Wc) {
            f_lds[hh][2 * p][c] = Fb[((size_t)c * Hc + hh) * Wc + w];
        }
    }

    // ---- stage depth: 30d x 28h x 4w as float2 ----
    for (int i = tid; i < DH * Hc * 2; i += 512) {     // 1680
        int dp = i / 56;
        int j2 = i % 56;
        int hh = j2 >> 1;
        int p  = j2 & 1;
        int dg = d0h + dp;
        int w  = w0 + 2 * p;
        if (dg < Dc && w + 1 < Wc) {
            float2 v = *(const float2*)(Db + ((size_t)dg * Hc + hh) * Wc + w);
            d_lds[dp][2 * p][hh]     = v.x;
            d_lds[dp][2 * p + 1][hh] = v.y;
        }
    }

    // ---- K inverse (exact f32 adjugate) ----
    const float* K = Kmat + (size_t)bn * 9;
    float k00 = K[0], k01 = K[1], k02 = K[2];
    float k10 = K[3], k11 = K[4], k12 = K[5];
    float k20 = K[6], k21 = K[7], k22 = K[8];
    float c00 = __fsub_rn(__fmul_rn(k11,k22), __fmul_rn(k12,k21));
    float c01 = __fsub_rn(__fmul_rn(k12,k20), __fmul_rn(k10,k22));
    float c02 = __fsub_rn(__fmul_rn(k10,k21), __fmul_rn(k11,k20));
    float det = __fadd_rn(__fadd_rn(__fmul_rn(k00,c00), __fmul_rn(k01,c01)), __fmul_rn(k02,c02));
    float i00 = __fdiv_rn(c00, det);
    float i01 = __fdiv_rn(__fsub_rn(__fmul_rn(k02,k21), __fmul_rn(k01,k22)), det);
    float i02 = __fdiv_rn(__fsub_rn(__fmul_rn(k01,k12), __fmul_rn(k02,k11)), det);
    float i10 = __fdiv_rn(c01, det);
    float i11 = __fdiv_rn(__fsub_rn(__fmul_rn(k00,k22), __fmul_rn(k02,k20)), det);
    float i12 = __fdiv_rn(__fsub_rn(__fmul_rn(k02,k10), __fmul_rn(k00,k12)), det);
    float i20 = __fdiv_rn(c02, det);
    float i21 = __fdiv_rn(__fsub_rn(__fmul_rn(k01,k20), __fmul_rn(k00,k21)), det);
    float i22 = __fdiv_rn(__fsub_rn(__fmul_rn(k00,k11), __fmul_rn(k01,k10)), det);

    const float* E = Emat + (size_t)bn * 16;
    float r00 = E[0], r01 = E[1], r02 = E[2],  tx = E[3];
    float r10 = E[4], r11 = E[5], r12 = E[6],  ty = E[7];
    float r20 = E[8], r21 = E[9], r22 = E[10], tz = E[11];

    __syncthreads();                     // single barrier: LDS ready

    float* accb = acc + (size_t)b * (BHc * BWc) * Cc;

    int wp   = wid >> 1;                 // w' 0..3
    int dsub = wid & 1;                  // 0..1
    int w    = w0 + wp;
    bool active = (w < Wc);

    int h = lane;
    float xf = (float)w;
    float yf = (float)h;
    int hl = (lane < Hc) ? lane : (Hc - 1);

    float accv[KPW];
    float mval[KPW];
    int   prim[KPW];

    // ---- Phase 1: geometry per (w, d); masked depth into registers ----
#pragma unroll
    for (int k = 0; k < KPW; ++k) {
        accv[k] = 0.0f;
        mval[k] = 0.0f;
        prim[k] = -1;
        int ld = dsub * KPW + k;
        int dg = d0h + ld;
        if (active && dg < Dc) {
            float db = (float)(dg + 1);          // depth bins 1..59
            float dep = (h < Hc) ? d_lds[ld][wp][hl] : 0.0f;

            float px = __fmul_rn(xf, db);
            float py = __fmul_rn(yf, db);
            float pz = db;

            float cx = __fadd_rn(__fadd_rn(__fmul_rn(i00, px), __fmul_rn(i01, py)), __fmul_rn(i02, pz));
            float cy = __fadd_rn(__fadd_rn(__fmul_rn(i10, px), __fmul_rn(i11, py)), __fmul_rn(i12, pz));
            float cz = __fadd_rn(__fadd_rn(__fmul_rn(i20, px), __fmul_rn(i21, py)), __fmul_rn(i22, pz));

            float ex = __fadd_rn(__fadd_rn(__fadd_rn(__fmul_rn(r00, cx), __fmul_rn(r01, cy)), __fmul_rn(r02, cz)), tx);
            float ey = __fadd_rn(__fadd_rn(__fadd_rn(__fmul_rn(r10, cx), __fmul_rn(r11, cy)), __fmul_rn(r12, cz)), ty);
            float ez = __fadd_rn(__fadd_rn(__fadd_rn(__fmul_rn(r20, cx), __fmul_rn(r21, cy)), __fmul_rn(r22, cz)), tz);

            int bx = (int)(__fmul_rn(__fadd_rn(ex, 50.0f), 2.0f));
            int by = (int)(__fmul_rn(__fadd_rn(ey, 50.0f), 2.0f));

            bool valid = (h < Hc) & (bx >= 0) & (bx < BWc) & (by >= 0) & (by < BHc) & (ez > 0.0f);
            int binidx = by * BWc + bx;

            unsigned long long vm = __ballot(valid);
            if (vm != 0ULL) {
                int first = __builtin_ctzll(vm);
                int pr = __shfl(binidx, first);
                unsigned long long match = __ballot(valid && (binidx == pr));
                unsigned long long rest2 = vm & ~match;
                prim[k] = pr;
                mval[k] = (valid && (binidx == pr)) ? dep : 0.0f;

                // fallback: valid h with a different bin (general case)
                while (rest2) {
                    int hh2 = __builtin_ctzll(rest2);
                    rest2 &= rest2 - 1;
                    int   bidx = __shfl(binidx, hh2);
                    float dv   = __shfl(dep, hh2);
                    atomicAdd(&accb[(size_t)bidx * Cc + lane],
                              __fmul_rn(f_lds[hh2][wp][lane], dv));
                }
            }
        }
    }

    // ---- Phase 2: dense h-matmul, depth broadcast via readlane ----
#pragma unroll
    for (int hh = 0; hh < Hc; ++hh) {
        float f = f_lds[hh][wp][lane];
#pragma unroll
        for (int k = 0; k < KPW; ++k) {
            float dk = __int_as_float(
                __builtin_amdgcn_readlane(__float_as_int(mval[k]), hh));
            accv[k] = __builtin_fmaf(f, dk, accv[k]);
        }
    }

    // ---- Phase 3: one 64-lane atomic per (w,d) ----
#pragma unroll
    for (int k = 0; k < KPW; ++k) {
        if (prim[k] >= 0)
            atomicAdd(&accb[(size_t)prim[k] * Cc + lane], accv[k]);
    }
}

// (B, BH*BW, C) -> (B, C, BH*BW), LDS-tiled 64x64
__global__ __launch_bounds__(256) void fp_transpose_kernel(
    const float* __restrict__ acc, float* __restrict__ out)
{
    __shared__ float tile[64][65];
    const int P = BHc * BWc;
    int b = blockIdx.y;
    int p0 = blockIdx.x * 64;
    int tx = threadIdx.x & 63;
    int ty = threadIdx.x >> 6;

    const float* src = acc + (size_t)b * P * Cc;
#pragma unroll
    for (int i = 0; i < 16; ++i) {
        int row = ty * 16 + i;
        tile[row][tx] = src[(size_t)(p0 + row) * Cc + tx];
    }
    __syncthreads();
    float* dst = out + (size_t)b * Cc * P;
#pragma unroll
    for (int i = 0; i < 16; ++i) {
        int c = ty * 16 + i;
        dst[(size_t)c * P + p0 + tx] = tile[tx][c];
    }
}

extern "C" void kernel_launch(void* const* d_in, const int* in_sizes, int n_in,
                              void* d_out, int out_size, void* d_ws, size_t ws_size,
                              hipStream_t stream) {
    const float* feats = (const float*)d_in[0];
    const float* depth = (const float*)d_in[1];
    const float* Kmat  = (const float*)d_in[2];
    const float* Emat  = (const float*)d_in[3];
    float* out = (float*)d_out;
    float* acc = (float*)d_ws;

    fp_zero<<<NZ, 256, 0, stream>>>(acc);
    fp_scatter7<<<NBLK, 512, 0, stream>>>(feats, depth, Kmat, Emat, acc);
    fp_transpose_kernel<<<dim3((BHc * BWc) / 64, Bc), 256, 0, stream>>>(acc, out);
}

// Round 12
// 100.797 us; speedup vs baseline: 1.4747x; 1.0149x over previous
//
#include <hip/hip_runtime.h>
#include <hip/hip_bf16.h>

// Problem constants
#define Bc 2
#define Nc 6
#define Cc 64
#define Hc 28
#define Wc 50
#define Dc 59
#define BHc 200
#define BWc 200
// BEV_X0 = BEV_Y0 = -50.0, RES = 0.5

#define NZ 640
#define ACC_ELEMS ((size_t)Bc * BHc * BWc * Cc)   // 5,120,000 floats

#define W4N 13            // ceil(50/4) w-groups
#define DQN 8             // d-chunks of 8
#define DCH 8             // d's per block
#define DWAVE 4           // d's per wave (wave = (w', dsub))
#define NBLK (12 * W4N * DQN)   // 1248 blocks

// ---------------------------------------------------------------------------
__global__ __launch_bounds__(256) void fp_zero(float* __restrict__ acc)
{
    const size_t NF4 = ACC_ELEMS / 4;
    float4* a4 = (float4*)acc;
    size_t base = (size_t)blockIdx.x * 2048;
#pragma unroll
    for (int it = 0; it < 8; ++it) {
        size_t i = base + (size_t)it * 256 + threadIdx.x;
        if (i < NF4) a4[i] = make_float4(0.f, 0.f, 0.f, 0.f);
    }
}

// ---------------------------------------------------------------------------
// Scatter v8: scatter5's grid shape (many blocks, DWAVE=4, ~10k waves) with
// scatter7's coalesced float2 staging from ORIGINAL layouts.
// Block = (bn, w4, dq): 512 threads, 8 waves; wave = (w'=wid>>1, dsub=wid&1),
// handling 4 d's. ONE barrier. Per (w,d): exact scatter5 logic.
__global__ __launch_bounds__(512) void fp_scatter8(
    const float* __restrict__ feats,   // (B,N,C,H,W)
    const float* __restrict__ depth,   // (B,N,D,H,W)
    const float* __restrict__ Kmat,    // (B,N,3,3)
    const float* __restrict__ Emat,    // (B,N,4,4)
    float* __restrict__ acc)           // (B, BH*BW, C)
{
    __shared__ float f_lds[Hc][4][65];    // 29.1 KB  [h][w'][c]
    __shared__ float d_lds[DCH][4][29];   //  3.7 KB  [d'][w'][h]

    // XCD-aware: 1248 = 8 * 156; xcd hosts 156 consecutive linear blocks
    int bid = blockIdx.x;
    int lin = (bid & 7) * 156 + (bid >> 3);   // bijective on [0,1248)
    int bn   = lin / 104;                     // 104 = 13 * 8
    int rest = lin % 104;
    int w4   = rest >> 3;
    int dq   = rest & 7;
    int b  = bn / Nc;
    int w0 = w4 * 4;
    int d0 = dq * DCH;

    int tid  = threadIdx.x;
    int lane = tid & 63;
    int wid  = tid >> 6;                 // 0..7

    const size_t HW = (size_t)Hc * Wc;
    const float* Fb = feats + (size_t)bn * Cc * HW;
    const float* Db = depth + (size_t)bn * Dc * HW;

    // ---- stage feats: 64c x 28h x 4w as float2 (w-contiguous) ----
    for (int i = tid; i < Cc * Hc * 2; i += 512) {     // 3584
        int c  = i / 56;
        int j2 = i % 56;
        int hh = j2 >> 1;
        int p  = j2 & 1;
        int w  = w0 + 2 * p;
        if (w + 1 < Wc) {
            float2 v = *(const float2*)(Fb + ((size_t)c * Hc + hh) * Wc + w);
            f_lds[hh][2 * p][c]     = v.x;
            f_lds[hh][2 * p + 1][c] = v.y;
        }
    }

    // ---- stage depth: 8d x 28h x 4w as float2 ----
    for (int i = tid; i < DCH * Hc * 2; i += 512) {    // 448
        int dp = i / 56;
        int j2 = i % 56;
        int hh = j2 >> 1;
        int p  = j2 & 1;
        int dg = d0 + dp;
        int w  = w0 + 2 * p;
        if (dg < Dc && w + 1 < Wc) {
            float2 v = *(const float2*)(Db + ((size_t)dg * Hc + hh) * Wc + w);
            d_lds[dp][2 * p][hh]     = v.x;
            d_lds[dp][2 * p + 1][hh] = v.y;
        }
    }

    // ---- K inverse (exact f32 adjugate) ----
    const float* K = Kmat + (size_t)bn * 9;
    float k00 = K[0], k01 = K[1], k02 = K[2];
    float k10 = K[3], k11 = K[4], k12 = K[5];
    float k20 = K[6], k21 = K[7], k22 = K[8];
    float c00 = __fsub_rn(__fmul_rn(k11,k22), __fmul_rn(k12,k21));
    float c01 = __fsub_rn(__fmul_rn(k12,k20), __fmul_rn(k10,k22));
    float c02 = __fsub_rn(__fmul_rn(k10,k21), __fmul_rn(k11,k20));
    float det = __fadd_rn(__fadd_rn(__fmul_rn(k00,c00), __fmul_rn(k01,c01)), __fmul_rn(k02,c02));
    float i00 = __fdiv_rn(c00, det);
    float i01 = __fdiv_rn(__fsub_rn(__fmul_rn(k02,k21), __fmul_rn(k01,k22)), det);
    float i02 = __fdiv_rn(__fsub_rn(__fmul_rn(k01,k12), __fmul_rn(k02,k11)), det);
    float i10 = __fdiv_rn(c01, det);
    float i11 = __fdiv_rn(__fsub_rn(__fmul_rn(k00,k22), __fmul_rn(k02,k20)), det);
    float i12 = __fdiv_rn(__fsub_rn(__fmul_rn(k02,k10), __fmul_rn(k00,k12)), det);
    float i20 = __fdiv_rn(c02, det);
    float i21 = __fdiv_rn(__fsub_rn(__fmul_rn(k01,k20), __fmul_rn(k00,k21)), det);
    float i22 = __fdiv_rn(__fsub_rn(__fmul_rn(k00,k11), __fmul_rn(k01,k10)), det);

    const float* E = Emat + (size_t)bn * 16;
    float r00 = E[0], r01 = E[1], r02 = E[2],  tx = E[3];
    float r10 = E[4], r11 = E[5], r12 = E[6],  ty = E[7];
    float r20 = E[8], r21 = E[9], r22 = E[10], tz = E[11];

    __syncthreads();                     // single barrier: LDS ready

    float* accb = acc + (size_t)b * (BHc * BWc) * Cc;

    int wp   = wid >> 1;                 // w' 0..3
    int dsub = wid & 1;                  // 0..1
    int w    = w0 + wp;
    bool active = (w < Wc);

    int h = lane;
    float xf = (float)w;
    float yf = (float)h;
    int hl = (lane < Hc) ? lane : (Hc - 1);

    float accv[DWAVE];
    float mval[DWAVE];
    int   prim[DWAVE];

    // ---- Phase 1: geometry per (w, d); masked depth into registers ----
#pragma unroll
    for (int k = 0; k < DWAVE; ++k) {
        accv[k] = 0.0f;
        mval[k] = 0.0f;
        prim[k] = -1;
        int ld = dsub * DWAVE + k;
        int dg = d0 + ld;
        if (active && dg < Dc) {
            float db = (float)(dg + 1);          // depth bins 1..59
            float dep = (h < Hc) ? d_lds[ld][wp][hl] : 0.0f;

            float px = __fmul_rn(xf, db);
            float py = __fmul_rn(yf, db);
            float pz = db;

            float cx = __fadd_rn(__fadd_rn(__fmul_rn(i00, px), __fmul_rn(i01, py)), __fmul_rn(i02, pz));
            float cy = __fadd_rn(__fadd_rn(__fmul_rn(i10, px), __fmul_rn(i11, py)), __fmul_rn(i12, pz));
            float cz = __fadd_rn(__fadd_rn(__fmul_rn(i20, px), __fmul_rn(i21, py)), __fmul_rn(i22, pz));

            float ex = __fadd_rn(__fadd_rn(__fadd_rn(__fmul_rn(r00, cx), __fmul_rn(r01, cy)), __fmul_rn(r02, cz)), tx);
            float ey = __fadd_rn(__fadd_rn(__fadd_rn(__fmul_rn(r10, cx), __fmul_rn(r11, cy)), __fmul_rn(r12, cz)), ty);
            float ez = __fadd_rn(__fadd_rn(__fadd_rn(__fmul_rn(r20, cx), __fmul_rn(r21, cy)), __fmul_rn(r22, cz)), tz);

            int bx = (int)(__fmul_rn(__fadd_rn(ex, 50.0f), 2.0f));
            int by = (int)(__fmul_rn(__fadd_rn(ey, 50.0f), 2.0f));

            bool valid = (h < Hc) & (bx >= 0) & (bx < BWc) & (by >= 0) & (by < BHc) & (ez > 0.0f);
            int binidx = by * BWc + bx;

            unsigned long long vm = __ballot(valid);
            if (vm != 0ULL) {
                int first = __builtin_ctzll(vm);
                int pr = __shfl(binidx, first);
                unsigned long long match = __ballot(valid && (binidx == pr));
                unsigned long long rest2 = vm & ~match;
                prim[k] = pr;
                mval[k] = (valid && (binidx == pr)) ? dep : 0.0f;

                // fallback: valid h with a different bin (general case)
                while (rest2) {
                    int hh2 = __builtin_ctzll(rest2);
                    rest2 &= rest2 - 1;
                    int   bidx = __shfl(binidx, hh2);
                    float dv   = __shfl(dep, hh2);
                    atomicAdd(&accb[(size_t)bidx * Cc + lane],
                              __fmul_rn(f_lds[hh2][wp][lane], dv));
                }
            }
        }
    }

    // ---- Phase 2: dense h-matmul, depth broadcast via readlane ----
#pragma unroll
    for (int hh = 0; hh < Hc; ++hh) {
        float f = f_lds[hh][wp][lane];
#pragma unroll
        for (int k = 0; k < DWAVE; ++k) {
            float dk = __int_as_float(
                __builtin_amdgcn_readlane(__float_as_int(mval[k]), hh));
            accv[k] = __builtin_fmaf(f, dk, accv[k]);
        }
    }

    // ---- Phase 3: one 64-lane atomic per (w,d) ----
#pragma unroll
    for (int k = 0; k < DWAVE; ++k) {
        if (prim[k] >= 0)
            atomicAdd(&accb[(size_t)prim[k] * Cc + lane], accv[k]);
    }
}

// (B, BH*BW, C) -> (B, C, BH*BW), LDS-tiled 64x64
__global__ __launch_bounds__(256) void fp_transpose_kernel(
    const float* __restrict__ acc, float* __restrict__ out)
{
    __shared__ float tile[64][65];
    const int P = BHc * BWc;
    int b = blockIdx.y;
    int p0 = blockIdx.x * 64;
    int tx = threadIdx.x & 63;
    int ty = threadIdx.x >> 6;

    const float* src = acc + (size_t)b * P * Cc;
#pragma unroll
    for (int i = 0; i < 16; ++i) {
        int row = ty * 16 + i;
        tile[row][tx] = src[(size_t)(p0 + row) * Cc + tx];
    }
    __syncthreads();
    float* dst = out + (size_t)b * Cc * P;
#pragma unroll
    for (int i = 0; i < 16; ++i) {
        int c = ty * 16 + i;
        dst[(size_t)c * P + p0 + tx] = tile[tx][c];
    }
}

extern "C" void kernel_launch(void* const* d_in, const int* in_sizes, int n_in,
                              void* d_out, int out_size, void* d_ws, size_t ws_size,
                              hipStream_t stream) {
    const float* feats = (const float*)d_in[0];
    const float* depth = (const float*)d_in[1];
    const float* Kmat  = (const float*)d_in[2];
    const float* Emat  = (const float*)d_in[3];
    float* out = (float*)d_out;
    float* acc = (float*)d_ws;

    fp_zero<<<NZ, 256, 0, stream>>>(acc);
    fp_scatter8<<<NBLK, 512, 0, stream>>>(feats, depth, Kmat, Emat, acc);
    fp_transpose_kernel<<<dim3((BHc * BWc) / 64, Bc), 256, 0, stream>>>(acc, out);
}